// Round 14
// baseline (734.359 us; speedup 1.0000x reference)
//
#include <hip/hip_runtime.h>

#define ENSN 256
#define XDIM 8192
#define YD 256
#define BATCH 8

// ws layout (float offsets)
#define OFF_Y   0          // [2048][256]            Y = Ens @ H
#define OFF_YC  524288     // [8][256(y)][256(e)]    Yc (transposed, centered)
#define OFF_AUG 1048576    // [8][256][512]          [A | innov] -> [LU | M1]
#define OFF_W   2097152    // [8][256(f)][256(e)]    W = Yc^T M1 / 256
#define OFF_XM  2621440    // [8][8192]              x_m
// scratch reuse:
//   Ht_hi/lo bf16[256][8192] at float-off 524288 / 1572864 (live kc_h..k2m)
//   Wt_hi/lo bf16[8][256][256] at float-off 0 / 262144 (Y region, dead after k3)
//   invU     f32 [8][8][32][32] at OFF_W (W region; dead until k6 writes W)

typedef __attribute__((ext_vector_type(4))) short short4v;
typedef __attribute__((ext_vector_type(8))) short short8v;
typedef __attribute__((ext_vector_type(4))) float float4v;

__device__ __forceinline__ unsigned short f2bf_rne(float x) {
    unsigned u = __float_as_uint(x);
    u += 0x7FFFu + ((u >> 16) & 1u);
    return (unsigned short)(u >> 16);
}

// ---------------- K1: x_m[b][x] = mean_e Ens[b,e,x] ----------------
__global__ __launch_bounds__(256) void k1_colmean(const float* __restrict__ E,
                                                  float* __restrict__ xm) {
    int x = blockIdx.x * 256 + threadIdx.x;
    int b = blockIdx.y;
    const float* p = E + (size_t)b * ENSN * XDIM + x;
    float s = 0.f;
    #pragma unroll 8
    for (int e = 0; e < ENSN; e++) s += p[(size_t)e * XDIM];
    xm[b * XDIM + x] = s * (1.0f / ENSN);
}

// ---------------- KC_H: H[8192][256] -> Ht_hi/lo[256][8192] bf16 (split, transposed) ----------------
__global__ __launch_bounds__(256) void kc_h(const float* __restrict__ H,
                                            short* __restrict__ Hthi,
                                            short* __restrict__ Htlo) {
    __shared__ float T[64][65];
    int k0 = blockIdx.x * 64, n0 = blockIdx.y * 64;
    int tid = threadIdx.x;
    int c = tid & 63, g = tid >> 6;
    #pragma unroll
    for (int p = 0; p < 16; p++)
        T[g + p * 4][c] = H[(size_t)(k0 + g + p * 4) * YD + n0 + c];
    __syncthreads();
    #pragma unroll
    for (int p = 0; p < 16; p++) {
        int nn = g + p * 4;
        float v = T[c][nn];
        unsigned short h = f2bf_rne(v);
        float hf = __uint_as_float(((unsigned)h) << 16);
        unsigned short l2 = f2bf_rne(v - hf);
        Hthi[(size_t)(n0 + nn) * XDIM + k0 + c] = (short)h;
        Htlo[(size_t)(n0 + nn) * XDIM + k0 + c] = (short)l2;
    }
}

// ---------------- K2M: Y = E @ H via bf16-split MFMA ----------------
// Fragment-contiguous LDS: tiles stored [tile][lane][8 shorts] so every frag
// read is lane*16B contiguous (minimal LDS cycles). LDS 51->40KB and
// split-K 32 (grid 1024 = 4 blocks/CU, launch_bounds(512,8)) hide the
// per-iter global->barrier drains that held MfmaUtil at 16%.
#define K2SPLIT 32
#define K2KB    (XDIM / K2SPLIT)   // 256 K per block, 8 iters of 32

__global__ __launch_bounds__(512, 8) void k2m_ygemm(const float* __restrict__ E,
                                                    const short* __restrict__ Hthi,
                                                    const short* __restrict__ Htlo,
                                                    float* __restrict__ Y) {
    __shared__ __align__(16) short Efh[4 * 64 * 8];    // [rowtile][lane][8]
    __shared__ __align__(16) short Efl[4 * 64 * 8];
    __shared__ __align__(16) short Bfh[16 * 64 * 8];   // [coltile][lane][8]
    __shared__ __align__(16) short Bfl[16 * 64 * 8];
    int tid = threadIdx.x;
    int lane = tid & 63;
    int w = tid >> 6;                  // wave 0..7
    int m0 = blockIdx.x * 64;
    int kb0 = blockIdx.y * K2KB;
    int wr = (w & 1) * 32;             // 2 row-waves
    int wc = (w >> 1) * 64;            // 4 col-waves
    float4v acc[8];
    #pragma unroll
    for (int i = 0; i < 8; i++) acc[i] = (float4v){0.f, 0.f, 0.f, 0.f};

    // E stage: erow = tid>>3 (64 rows), 4 floats at (tid&7)*4 -> half-frag
    int erow = tid >> 3, ecol = (tid & 7) * 4;
    int efg = (tid & 7) >> 1, ehalf = tid & 1;
    int ebase = (((erow >> 4) * 64 + efg * 16 + (erow & 15)) << 3) + ehalf * 4;
    // B stage: row = tid>>1 (256 rows), 16 shorts at (tid&1)*16 -> frags 2f,2f+1
    int brow = tid >> 1, bf0 = (tid & 1) * 2;
    int bbase0 = (((brow >> 4) * 64 + (bf0 + 0) * 16 + (brow & 15)) << 3);
    int bbase1 = (((brow >> 4) * 64 + (bf0 + 1) * 16 + (brow & 15)) << 3);
    int fr = lane & 15, fg = lane >> 4;

    for (int s = 0; s < K2KB / 32; s++) {
        int kb = kb0 + s * 32;
        float4 ev = *(const float4*)&E[(size_t)(m0 + erow) * XDIM + kb + ecol];
        float vv[4] = {ev.x, ev.y, ev.z, ev.w};
        short4v hi4, lo4;
        #pragma unroll
        for (int j = 0; j < 4; j++) {
            unsigned short h = f2bf_rne(vv[j]);
            float hf = __uint_as_float(((unsigned)h) << 16);
            unsigned short l2 = f2bf_rne(vv[j] - hf);
            hi4[j] = (short)h; lo4[j] = (short)l2;
        }
        *(short4v*)&Efh[ebase] = hi4;
        *(short4v*)&Efl[ebase] = lo4;
        short8v bh0 = *(const short8v*)&Hthi[(size_t)brow * XDIM + kb + bf0 * 8];
        short8v bh1 = *(const short8v*)&Hthi[(size_t)brow * XDIM + kb + bf0 * 8 + 8];
        short8v bl0 = *(const short8v*)&Htlo[(size_t)brow * XDIM + kb + bf0 * 8];
        short8v bl1 = *(const short8v*)&Htlo[(size_t)brow * XDIM + kb + bf0 * 8 + 8];
        *(short8v*)&Bfh[bbase0] = bh0;
        *(short8v*)&Bfh[bbase1] = bh1;
        *(short8v*)&Bfl[bbase0] = bl0;
        *(short8v*)&Bfl[bbase1] = bl1;
        __syncthreads();
        short8v ah[2], al[2], bhf[4], blf[4];
        #pragma unroll
        for (int ti = 0; ti < 2; ti++) {
            int t = ((wr >> 4) + ti) * 512 + lane * 8;
            ah[ti] = *(const short8v*)&Efh[t];
            al[ti] = *(const short8v*)&Efl[t];
        }
        #pragma unroll
        for (int tj = 0; tj < 4; tj++) {
            int t = ((wc >> 4) + tj) * 512 + lane * 8;
            bhf[tj] = *(const short8v*)&Bfh[t];
            blf[tj] = *(const short8v*)&Bfl[t];
        }
        #pragma unroll
        for (int ti = 0; ti < 2; ti++)
            #pragma unroll
            for (int tj = 0; tj < 4; tj++) {
                int a = ti * 4 + tj;
                acc[a] = __builtin_amdgcn_mfma_f32_16x16x32_bf16(ah[ti], bhf[tj], acc[a], 0, 0, 0);
                acc[a] = __builtin_amdgcn_mfma_f32_16x16x32_bf16(ah[ti], blf[tj], acc[a], 0, 0, 0);
                acc[a] = __builtin_amdgcn_mfma_f32_16x16x32_bf16(al[ti], bhf[tj], acc[a], 0, 0, 0);
            }
        __syncthreads();
    }
    #pragma unroll
    for (int ti = 0; ti < 2; ti++)
        #pragma unroll
        for (int tj = 0; tj < 4; tj++)
            #pragma unroll
            for (int q = 0; q < 4; q++) {
                int row = m0 + wr + ti * 16 + fg * 4 + q;
                int col = wc + tj * 16 + fr;
                atomicAdd(&Y[row * YD + col], acc[ti * 4 + tj][q]);
            }
}

// ---------------- K3: y_m, Yc[y][e], innov -> aug right half ----------------
__global__ __launch_bounds__(256) void k3_center(const float* __restrict__ Y,
                                                 const float* __restrict__ ytm,
                                                 const float* __restrict__ ystd,
                                                 const float* __restrict__ noise,
                                                 float* __restrict__ Yc,
                                                 float* __restrict__ aug) {
    int b = blockIdx.y, tid = threadIdx.x;
    int y0 = blockIdx.x * 64;
    __shared__ float red[4][64];
    __shared__ float ym[64], tms[64], s2[64];
    __shared__ float T[64][65];
    int yl = tid & 63, q = tid >> 6;
    float s = 0.f;
    for (int e = q * 64; e < q * 64 + 64; e++)
        s += Y[(size_t)(b * ENSN + e) * YD + y0 + yl];
    red[q][yl] = s;
    __syncthreads();
    if (tid < 64) {
        ym[tid] = (red[0][tid] + red[1][tid] + red[2][tid] + red[3][tid]) * (1.0f / ENSN);
        float sd = ystd[y0 + tid];
        s2[tid] = sd * sd;
        tms[tid] = ytm[y0 + tid];
    }
    __syncthreads();
    for (int e0 = 0; e0 < ENSN; e0 += 64) {
        #pragma unroll
        for (int p = 0; p < 16; p++) {
            int er = q + p * 4;
            T[er][yl] = Y[(size_t)(b * ENSN + e0 + er) * YD + y0 + yl];
        }
        __syncthreads();
        int ec = yl;
        #pragma unroll
        for (int p = 0; p < 16; p++) {
            int yr = q + p * 4;
            int y = y0 + yr, e = e0 + ec;
            float yv = T[ec][yr] - ym[yr];
            Yc[(size_t)b * YD * ENSN + (size_t)y * ENSN + e] = yv;
            aug[(size_t)b * YD * 512 + (size_t)y * 512 + 256 + e] =
                tms[yr] - yv + noise[(size_t)b * YD * ENSN + (size_t)y * ENSN + e] * s2[yr];
        }
        __syncthreads();
    }
}

// ---------------- K4: A = Yc Yc^T / 256 + diag(std^2) -> aug left half ----------------
__global__ __launch_bounds__(256) void k4_cyy(const float* __restrict__ Yc,
                                              const float* __restrict__ ystd,
                                              float* __restrict__ aug) {
    __shared__ float As[16][68];
    __shared__ float Bs[16][68];
    int tid = threadIdx.x;
    int m0 = blockIdx.x * 64, n0 = blockIdx.y * 64, b = blockIdx.z;
    const float* Ycb = Yc + (size_t)b * YD * ENSN;
    int tr = tid >> 4, tc = tid & 15;
    float acc[4][4];
    #pragma unroll
    for (int i = 0; i < 4; i++)
        #pragma unroll
        for (int j = 0; j < 4; j++) acc[i][j] = 0.f;
    int al = tid & 15, am0 = tid >> 4;
    for (int k0 = 0; k0 < ENSN; k0 += 16) {
        #pragma unroll
        for (int p = 0; p < 4; p++) {
            int am = am0 + p * 16;
            As[al][am] = Ycb[(m0 + am) * ENSN + k0 + al];
            Bs[al][am] = Ycb[(n0 + am) * ENSN + k0 + al];
        }
        __syncthreads();
        #pragma unroll
        for (int kk = 0; kk < 16; kk++) {
            float4 a = *(const float4*)&As[kk][tr * 4];
            float4 bb = *(const float4*)&Bs[kk][tc * 4];
            float af[4] = {a.x, a.y, a.z, a.w};
            float bf[4] = {bb.x, bb.y, bb.z, bb.w};
            #pragma unroll
            for (int i = 0; i < 4; i++)
                #pragma unroll
                for (int j = 0; j < 4; j++) acc[i][j] += af[i] * bf[j];
        }
        __syncthreads();
    }
    float* augb = aug + (size_t)b * YD * 512;
    #pragma unroll
    for (int i = 0; i < 4; i++) {
        int u = m0 + tr * 4 + i;
        #pragma unroll
        for (int j = 0; j < 4; j++) {
            int v = n0 + tc * 4 + j;
            float val = acc[i][j] * (1.0f / ENSN);
            if (u == v) { float sv = ystd[u]; val += sv * sv; }
            augb[u * 512 + v] = val;
        }
    }
}

// ---------------- K5p: panel factor+solve for panel p (c0 = 32p) ----------------
// Round-11 form: serial 32-step per-thread solves hidden by 16-wave TLP.
#define RSTP 484
#define LSTP 233

__global__ __launch_bounds__(1024, 4) void k5p_panel(float* __restrict__ aug, int c0) {
    __shared__ __align__(16) float R[32 * RSTP];
    __shared__ float Ls[32 * LSTP];
    __shared__ __align__(16) float Dg[32 * 33];
    __shared__ float invd[32];
    int b = blockIdx.x, tid = threadIdx.x;
    float* A = aug + (size_t)b * 256 * 512;
    int r5 = tid >> 5, c5 = tid & 31;
    int WR = 480 - c0;
    int W2 = 224 - c0;

    Dg[r5 * 33 + c5] = A[(c0 + r5) * 512 + c0 + c5];
    __syncthreads();
    if (tid < 32) {
        float u[32];
        #pragma unroll
        for (int c = 0; c < 32; c++) u[c] = Dg[tid * 33 + c];
        for (int j = 0; j < 31; j++) {
            float pv = __shfl(u[j], j);
            float f = u[j] / pv;
            #pragma unroll
            for (int c = 0; c < 32; c++) {
                if (c > j) {
                    float ujc = __shfl(u[c], j);
                    if (tid > j) u[c] -= f * ujc;
                }
            }
            if (tid > j) u[j] = f;
        }
        #pragma unroll
        for (int c = 0; c < 32; c++) Dg[tid * 33 + c] = u[c];
        invd[tid] = 1.0f / u[tid];
    }
    for (int cc = c5; cc < WR; cc += 32)
        R[r5 * RSTP + cc] = A[(c0 + r5) * 512 + c0 + 32 + cc];
    for (int row = r5; row < W2; row += 32)
        Ls[c5 * LSTP + row] = A[(c0 + 32 + row) * 512 + c0 + c5];
    __syncthreads();
    A[(c0 + r5) * 512 + c0 + c5] = Dg[r5 * 33 + c5];
    if (tid < WR) {
        float y[32];
        #pragma unroll
        for (int j = 0; j < 32; j++) {
            float s = R[j * RSTP + tid];
            #pragma unroll
            for (int m = 0; m < 32; m++)
                if (m < j) s -= Dg[j * 33 + m] * y[m];
            y[j] = s;
        }
        #pragma unroll
        for (int j = 0; j < 32; j++)
            A[(c0 + j) * 512 + c0 + 32 + tid] = y[j];
    }
    if (tid >= 512 && tid < 512 + W2) {
        int row = tid - 512;
        float l[32];
        #pragma unroll
        for (int j = 0; j < 32; j++) {
            float s = Ls[j * LSTP + row];
            #pragma unroll
            for (int m = 0; m < 32; m++)
                if (m < j) s -= l[m] * Dg[m * 33 + j];
            l[j] = s * invd[j];
        }
        #pragma unroll
        for (int j = 0; j < 32; j++)
            Ls[j * LSTP + row] = l[j];
    }
    __syncthreads();
    for (int row = r5; row < W2; row += 32)
        A[(c0 + 32 + row) * 512 + c0 + c5] = Ls[c5 * LSTP + row];
}

// ---------------- K5t: trailing update [A22|Z] -= L21 * [U12|Y] ----------------
__global__ __launch_bounds__(256) void k5t_trail(float* __restrict__ aug, int c0) {
    __shared__ __align__(16) float Lt[32][36];
    __shared__ __align__(16) float Ut[32][36];
    int b = blockIdx.z, tid = threadIdx.x;
    float* A = aug + (size_t)b * 256 * 512;
    int r0  = c0 + 32 + blockIdx.x * 32;
    int cc0 = c0 + 32 + blockIdx.y * 32;
    int lr = tid >> 3, lc = (tid & 7) * 4;
    *(float4*)&Lt[lr][lc] = *(const float4*)&A[(size_t)(r0 + lr) * 512 + c0 + lc];
    *(float4*)&Ut[lr][lc] = *(const float4*)&A[(size_t)(c0 + lr) * 512 + cc0 + lc];
    __syncthreads();
    float* gp = &A[(size_t)(r0 + lr) * 512 + cc0 + lc];
    float4 acc = *(const float4*)gp;
    #pragma unroll
    for (int k = 0; k < 32; k++) {
        float lv = Lt[lr][k];
        float4 uv = *(const float4*)&Ut[k][lc];
        acc.x -= lv * uv.x;
        acc.y -= lv * uv.y;
        acc.z -= lv * uv.z;
        acc.w -= lv * uv.w;
    }
    *(float4*)gp = acc;
}

// ---------------- K5I: invU[b][p] = inv(U_pp) (32x32 upper) ----------------
__global__ __launch_bounds__(64) void k5i_invu(const float* __restrict__ aug,
                                               float* __restrict__ invU) {
    __shared__ float Dg[32 * 33];
    __shared__ float invd[32];
    int p = blockIdx.x, b = blockIdx.y, tid = threadIdx.x;
    const float* A = aug + (size_t)b * 256 * 512;
    int c0 = 32 * p;
    for (int i = tid; i < 1024; i += 64)
        Dg[(i >> 5) * 33 + (i & 31)] = A[(size_t)(c0 + (i >> 5)) * 512 + c0 + (i & 31)];
    __syncthreads();
    if (tid < 32) invd[tid] = 1.0f / Dg[tid * 33 + tid];
    __syncthreads();
    if (tid < 32) {
        int c = tid;
        float x[32];
        #pragma unroll
        for (int j = 31; j >= 0; j--) {
            float s = (j == c) ? 1.0f : 0.0f;
            #pragma unroll
            for (int m = 0; m < 32; m++)
                if (m > j) s -= Dg[j * 33 + m] * x[m];
            x[j] = s * invd[j];
        }
        float* op = invU + (size_t)(b * 8 + p) * 1024;
        #pragma unroll
        for (int j = 0; j < 32; j++) op[j * 32 + c] = x[j];
    }
}

// ---------------- K5s: backward sweep via X = invU * Z, 32 cols/block ----------------
#define ZST  36
#define LBST 36

__global__ __launch_bounds__(512, 2) void k5s_solve(float* __restrict__ aug,
                                                    const float* __restrict__ invU) {
    __shared__ __align__(16) float Zs[256 * ZST];
    __shared__ __align__(16) float Lb[224 * LBST];
    __shared__ __align__(16) float Dg[32 * 33];
    int b = blockIdx.y, tid = threadIdx.x;
    float* A = aug + (size_t)b * 256 * 512;
    int cb = blockIdx.x * 32;
    int c = tid & 31, g = tid >> 5;       // g in 0..15
    int rr = tid >> 5, cc = tid & 31;

    for (int r = g; r < 256; r += 16)
        Zs[r * ZST + c] = A[r * 512 + 256 + cb + c];

    for (int p = 7; p >= 0; p--) {
        int c0 = 32 * p, na = c0;
        for (int i = tid; i < 1024; i += 512)
            Dg[(i >> 5) * 33 + (i & 31)] = invU[(size_t)(b * 8 + p) * 1024 + i];
        for (int r = rr; r < na; r += 16)
            Lb[r * LBST + cc] = A[r * 512 + c0 + cc];
        __syncthreads();
        float z[32];
        #pragma unroll
        for (int m = 0; m < 32; m++) z[m] = Zs[(c0 + m) * ZST + c];
        float xr[2];
        #pragma unroll
        for (int r2 = 0; r2 < 2; r2++) {
            const float* dr = &Dg[(g * 2 + r2) * 33];
            float s0 = 0.f, s1 = 0.f, s2 = 0.f, s3 = 0.f;
            #pragma unroll
            for (int m = 0; m < 32; m += 4) {
                s0 += dr[m + 0] * z[m + 0];
                s1 += dr[m + 1] * z[m + 1];
                s2 += dr[m + 2] * z[m + 2];
                s3 += dr[m + 3] * z[m + 3];
            }
            xr[r2] = (s0 + s1) + (s2 + s3);
        }
        __syncthreads();
        #pragma unroll
        for (int r2 = 0; r2 < 2; r2++)
            Zs[(c0 + g * 2 + r2) * ZST + c] = xr[r2];
        __syncthreads();
        if (na > 0) {
            float zx[32];
            #pragma unroll
            for (int k = 0; k < 32; k++) zx[k] = Zs[(c0 + k) * ZST + c];
            for (int r = g; r < na; r += 16) {
                const float* lp = &Lb[r * LBST];
                float a0 = 0.f, a1 = 0.f, a2 = 0.f, a3 = 0.f;
                #pragma unroll
                for (int k = 0; k < 32; k += 4) {
                    float4 lv = *(const float4*)(lp + k);
                    a0 += lv.x * zx[k + 0];
                    a1 += lv.y * zx[k + 1];
                    a2 += lv.z * zx[k + 2];
                    a3 += lv.w * zx[k + 3];
                }
                Zs[r * ZST + c] -= (a0 + a1) + (a2 + a3);
            }
        }
        __syncthreads();
    }

    for (int r = g; r < 256; r += 16)
        A[r * 512 + 256 + cb + c] = Zs[r * ZST + c];
}

// ---------------- K6: W[f][e] = sum_y Yc[y][f] * M1[y][e] / 256 ----------------
__global__ __launch_bounds__(256) void k6_w(const float* __restrict__ Yc,
                                            const float* __restrict__ aug,
                                            float* __restrict__ W) {
    __shared__ float As[16][68];
    __shared__ float Bs[16][68];
    int tid = threadIdx.x;
    int m0 = blockIdx.x * 64, n0 = blockIdx.y * 64, b = blockIdx.z;
    const float* Ycb = Yc + (size_t)b * YD * ENSN;
    const float* augb = aug + (size_t)b * YD * 512;
    int tr = tid >> 4, tc = tid & 15;
    float acc[4][4];
    #pragma unroll
    for (int i = 0; i < 4; i++)
        #pragma unroll
        for (int j = 0; j < 4; j++) acc[i][j] = 0.f;
    int c = tid & 63, kr0 = tid >> 6;
    for (int k0 = 0; k0 < YD; k0 += 16) {
        #pragma unroll
        for (int p = 0; p < 4; p++) {
            int kk = kr0 + p * 4;
            As[kk][c] = Ycb[(k0 + kk) * ENSN + m0 + c];
            Bs[kk][c] = augb[(k0 + kk) * 512 + 256 + n0 + c];
        }
        __syncthreads();
        #pragma unroll
        for (int kk = 0; kk < 16; kk++) {
            float4 a = *(const float4*)&As[kk][tr * 4];
            float4 bb = *(const float4*)&Bs[kk][tc * 4];
            float af[4] = {a.x, a.y, a.z, a.w};
            float bf[4] = {bb.x, bb.y, bb.z, bb.w};
            #pragma unroll
            for (int i = 0; i < 4; i++)
                #pragma unroll
                for (int j = 0; j < 4; j++) acc[i][j] += af[i] * bf[j];
        }
        __syncthreads();
    }
    float* Wb = W + (size_t)b * ENSN * ENSN;
    #pragma unroll
    for (int i = 0; i < 4; i++)
        #pragma unroll
        for (int j = 0; j < 4; j++)
            Wb[(m0 + tr * 4 + i) * ENSN + n0 + tc * 4 + j] = acc[i][j] * (1.0f / ENSN);
}

// ---------------- KW_W: W[f][e] -> Wt_hi/lo[e][f] bf16 (split, transposed) ----------------
__global__ __launch_bounds__(256) void kw_w(const float* __restrict__ W,
                                            short* __restrict__ Wthi,
                                            short* __restrict__ Wtlo) {
    __shared__ float T[64][65];
    int f0 = blockIdx.x * 64, e0 = blockIdx.y * 64, b = blockIdx.z;
    const float* Wb = W + (size_t)b * ENSN * ENSN;
    int tid = threadIdx.x;
    int c = tid & 63, g = tid >> 6;
    #pragma unroll
    for (int p = 0; p < 16; p++)
        T[g + p * 4][c] = Wb[(size_t)(f0 + g + p * 4) * ENSN + e0 + c];
    __syncthreads();
    #pragma unroll
    for (int p = 0; p < 16; p++) {
        int ee = g + p * 4;
        float v = T[c][ee];   // = W[f0+c][e0+ee]
        unsigned short h = f2bf_rne(v);
        float hf = __uint_as_float(((unsigned)h) << 16);
        unsigned short l2 = f2bf_rne(v - hf);
        size_t o = (size_t)b * ENSN * ENSN + (size_t)(e0 + ee) * ENSN + f0 + c;
        Wthi[o] = (short)h;
        Wtlo[o] = (short)l2;
    }
}

// ---------------- K7M: out = E + Wt MFMA update, fragment-contiguous LDS ----------------
// A = Wt [16 tiles][64][8]; B = Ec [4 tiles][64][8] (converted in-kernel).
__global__ __launch_bounds__(512, 4) void k7m_update(const float* __restrict__ E,
                                                     const short* __restrict__ Wthi,
                                                     const short* __restrict__ Wtlo,
                                                     const float* __restrict__ xm,
                                                     float* __restrict__ out) {
    __shared__ __align__(16) short Afh[16 * 64 * 8];
    __shared__ __align__(16) short Afl[16 * 64 * 8];
    __shared__ __align__(16) short Bfh[4 * 64 * 8];
    __shared__ __align__(16) short Bfl[4 * 64 * 8];
    __shared__ float xs[64];
    int tid = threadIdx.x;
    int lane = tid & 63;
    int w = tid >> 6;
    int x0 = blockIdx.x * 64;
    int b = blockIdx.y;
    const short* Whb = Wthi + (size_t)b * ENSN * ENSN;
    const short* Wlb = Wtlo + (size_t)b * ENSN * ENSN;
    const float* Eb = E + (size_t)b * ENSN * XDIM;
    if (tid < 64) xs[tid] = xm[b * XDIM + x0 + tid];
    __syncthreads();
    int wr = (w & 3) * 64;    // wave M offset (e)
    int wc = (w >> 2) * 32;   // wave N offset (x)
    float4v acc[8];
    #pragma unroll
    for (int i = 0; i < 8; i++) acc[i] = (float4v){0.f, 0.f, 0.f, 0.f};
    int fr = lane & 15, fg = lane >> 4;
    // A stage: row = tid>>1 (0..255), frags (row, 2(tid&1)) and (row, 2(tid&1)+1)
    int arow = tid >> 1, af0 = (tid & 1) * 2;
    int abase0 = (((arow >> 4) * 64 + (af0 + 0) * 16 + (arow & 15)) << 3);
    int abase1 = (((arow >> 4) * 64 + (af0 + 1) * 16 + (arow & 15)) << 3);
    // B stage: x = tid&63, k-quad = tid>>6 -> half-frag of (x, fg=(tid>>6)>>1)
    int bx = tid & 63, bkq = tid >> 6;
    int bfg = bkq >> 1, bhalf = bkq & 1;
    int bbase = (((bx >> 4) * 64 + bfg * 16 + (bx & 15)) << 3) + bhalf * 4;

    for (int s = 0; s < 8; s++) {
        int k0 = s * 32;
        *(short8v*)&Afh[abase0] = *(const short8v*)&Whb[(size_t)arow * ENSN + k0 + af0 * 8];
        *(short8v*)&Afh[abase1] = *(const short8v*)&Whb[(size_t)arow * ENSN + k0 + af0 * 8 + 8];
        *(short8v*)&Afl[abase0] = *(const short8v*)&Wlb[(size_t)arow * ENSN + k0 + af0 * 8];
        *(short8v*)&Afl[abase1] = *(const short8v*)&Wlb[(size_t)arow * ENSN + k0 + af0 * 8 + 8];
        short4v hi4, lo4;
        #pragma unroll
        for (int j = 0; j < 4; j++) {
            float v = Eb[(size_t)(k0 + bkq * 4 + j) * XDIM + x0 + bx] - xs[bx];
            unsigned short h = f2bf_rne(v);
            float hf = __uint_as_float(((unsigned)h) << 16);
            unsigned short l2 = f2bf_rne(v - hf);
            hi4[j] = (short)h; lo4[j] = (short)l2;
        }
        *(short4v*)&Bfh[bbase] = hi4;
        *(short4v*)&Bfl[bbase] = lo4;
        __syncthreads();
        short8v ah[4], al[4], bhf[2], blf[2];
        #pragma unroll
        for (int ti = 0; ti < 4; ti++) {
            int t = ((wr >> 4) + ti) * 512 + lane * 8;
            ah[ti] = *(const short8v*)&Afh[t];
            al[ti] = *(const short8v*)&Afl[t];
        }
        #pragma unroll
        for (int tj = 0; tj < 2; tj++) {
            int t = ((wc >> 4) + tj) * 512 + lane * 8;
            bhf[tj] = *(const short8v*)&Bfh[t];
            blf[tj] = *(const short8v*)&Bfl[t];
        }
        #pragma unroll
        for (int ti = 0; ti < 4; ti++)
            #pragma unroll
            for (int tj = 0; tj < 2; tj++) {
                int a = ti * 2 + tj;
                acc[a] = __builtin_amdgcn_mfma_f32_16x16x32_bf16(ah[ti], bhf[tj], acc[a], 0, 0, 0);
                acc[a] = __builtin_amdgcn_mfma_f32_16x16x32_bf16(ah[ti], blf[tj], acc[a], 0, 0, 0);
                acc[a] = __builtin_amdgcn_mfma_f32_16x16x32_bf16(al[ti], bhf[tj], acc[a], 0, 0, 0);
            }
        __syncthreads();
    }
    #pragma unroll
    for (int ti = 0; ti < 4; ti++)
        #pragma unroll
        for (int tj = 0; tj < 2; tj++)
            #pragma unroll
            for (int q = 0; q < 4; q++) {
                int e = wr + ti * 16 + fg * 4 + q;
                int x = x0 + wc + tj * 16 + fr;
                size_t idx = (size_t)(b * ENSN + e) * XDIM + x;
                out[idx] = E[idx] + acc[ti * 2 + tj][q];
            }
}

extern "C" void kernel_launch(void* const* d_in, const int* in_sizes, int n_in,
                              void* d_out, int out_size, void* d_ws, size_t ws_size,
                              hipStream_t stream) {
    const float* Ens   = (const float*)d_in[0];  // [8,256,8192]
    const float* H     = (const float*)d_in[1];  // [8192,256]
    const float* ytm   = (const float*)d_in[2];  // [1,256]
    const float* ystd  = (const float*)d_in[3];  // [1,256]
    const float* noise = (const float*)d_in[4];  // [8,256,256]
    float* out = (float*)d_out;
    float* ws  = (float*)d_ws;

    float* Y   = ws + OFF_Y;
    float* Yc  = ws + OFF_YC;
    float* aug = ws + OFF_AUG;
    float* W   = ws + OFF_W;
    float* xm  = ws + OFF_XM;
    // bf16-split transposed H (Yc/aug span; dead once k2m finishes)
    short* Hthi = (short*)(ws + 524288);    // 256x8192 bf16
    short* Htlo = (short*)(ws + 1572864);   // 256x8192 bf16
    // bf16-split transposed W (Y span; Y is dead after k3)
    short* Wthi = (short*)(ws + 0);         // 8x256x256 bf16 = 262144 floats
    short* Wtlo = (short*)(ws + 262144);    // 8x256x256 bf16
    // invU in the W region (dead until k6 writes W): 8*8*1024 = 65536 floats
    float* invU = ws + OFF_W;

    hipMemsetAsync(Y, 0, (size_t)2048 * 256 * sizeof(float), stream);

    k1_colmean<<<dim3(XDIM / 256, BATCH), 256, 0, stream>>>(Ens, xm);
    kc_h<<<dim3(XDIM / 64, YD / 64), 256, 0, stream>>>(H, Hthi, Htlo);
    k2m_ygemm<<<dim3(2048 / 64, K2SPLIT), 512, 0, stream>>>(Ens, Hthi, Htlo, Y);
    k3_center<<<dim3(4, BATCH), 256, 0, stream>>>(Y, ytm, ystd, noise, Yc, aug);
    k4_cyy<<<dim3(4, 4, BATCH), 256, 0, stream>>>(Yc, ystd, aug);
    for (int p = 0; p < 8; p++) {
        k5p_panel<<<dim3(BATCH), 1024, 0, stream>>>(aug, 32 * p);
        if (p < 7)
            k5t_trail<<<dim3(7 - p, 15 - p, BATCH), 256, 0, stream>>>(aug, 32 * p);
    }
    k5i_invu<<<dim3(8, BATCH), 64, 0, stream>>>(aug, invU);
    k5s_solve<<<dim3(8, BATCH), 512, 0, stream>>>(aug, invU);
    k6_w<<<dim3(4, 4, BATCH), 256, 0, stream>>>(Yc, aug, W);
    kw_w<<<dim3(4, 4, BATCH), 256, 0, stream>>>(W, Wthi, Wtlo);
    k7m_update<<<dim3(XDIM / 64, BATCH), 512, 0, stream>>>(Ens, Wthi, Wtlo, xm, out);
}